// Round 3
// baseline (1465.059 us; speedup 1.0000x reference)
//
#include <hip/hip_runtime.h>
#include <hip/hip_bf16.h>

#define B_   128
#define L_   512
#define E_   512
#define H_   256
#define K_   64
#define G4H  1024   // 4*H
#define LOG2E 1.4426950408889634f

typedef __bf16 bf16x8 __attribute__((ext_vector_type(8)));
typedef float  f32x4  __attribute__((ext_vector_type(4)));
typedef int    i32x8  __attribute__((ext_vector_type(8)));

__device__ inline unsigned short f2bf(float f) {
    unsigned int x = __builtin_bit_cast(unsigned int, f);
    unsigned int r = (x + 0x7fffu + ((x >> 16) & 1u)) >> 16;
    return (unsigned short)r;
}
__device__ inline float bf2f(unsigned short u) {
    unsigned int x = ((unsigned int)u) << 16;
    return __builtin_bit_cast(float, x);
}
__device__ inline unsigned int pack2(float lo, float hi) {
    return (unsigned int)f2bf(lo) | ((unsigned int)f2bf(hi) << 16);
}
__device__ inline float ex2(float x) { return __builtin_amdgcn_exp2f(x); }
__device__ inline float rcp_(float x) { return __builtin_amdgcn_rcpf(x); }

// async global->LDS, 16B per lane; LDS dest must be wave-uniform + lane*16
__device__ inline void gl_lds16(const unsigned short* g, unsigned short* l) {
    __builtin_amdgcn_global_load_lds(
        (const __attribute__((address_space(1))) unsigned int*)g,
        (__attribute__((address_space(3))) unsigned int*)l, 16, 0, 0);
}

// ---------------------------------------------------------------------------
// Setup: whh -> fp8 e4m3 scaled by LOG2E; w_emit -> bf16;
// w_ih -> bf16 * LOG2E with gate-interleaved row perm wp[n'=col*4+gate];
// bias_p = (b_ih + b_hh) * LOG2E, permuted.
// ---------------------------------------------------------------------------
__global__ void setup_convert(const float* __restrict__ whh_f, const float* __restrict__ whh_b,
                              const float* __restrict__ wemit,
                              const float* __restrict__ wihf, const float* __restrict__ wihb,
                              const float* __restrict__ bihf, const float* __restrict__ bhhf,
                              const float* __restrict__ bihb, const float* __restrict__ bhhb,
                              unsigned char* __restrict__ whh8,
                              unsigned short* __restrict__ wemit_bf,
                              unsigned short* __restrict__ wp,
                              float* __restrict__ bias_p) {
    int i = blockIdx.x * 256 + threadIdx.x;       // grid 1024*256 = 262144
    if (i < 262144) {
        int j = 2 * i;
        float v0 = (j < 262144) ? whh_f[j] : whh_b[j - 262144];
        float v1 = (j + 1 < 262144) ? whh_f[j + 1] : whh_b[j + 1 - 262144];
        int pk = __builtin_amdgcn_cvt_pk_fp8_f32(v0 * LOG2E, v1 * LOG2E, 0, false);
        ((unsigned short*)whh8)[i] = (unsigned short)(pk & 0xffff);
    }
    if (i < K_ * 2 * H_) wemit_bf[i] = f2bf(wemit[i]);
    if (i < 131072) {
        int rp = i >> 6;            // permuted row 0..2047
        int k8 = (i & 63) * 8;
        int dd = rp >> 10, np = rp & 1023;
        int srow = (np & 3) * 256 + (np >> 2);
        const float* src = (dd == 0 ? wihf : wihb) + (size_t)srow * 512 + k8;
        float4 a  = *reinterpret_cast<const float4*>(src);
        float4 b2 = *reinterpret_cast<const float4*>(src + 4);
        uint4 pk = { pack2(a.x * LOG2E, a.y * LOG2E), pack2(a.z * LOG2E, a.w * LOG2E),
                     pack2(b2.x * LOG2E, b2.y * LOG2E), pack2(b2.z * LOG2E, b2.w * LOG2E) };
        *reinterpret_cast<uint4*>(wp + (size_t)rp * 512 + k8) = pk;
    }
    if (i < 2048) {
        int dd = i >> 10, np = i & 1023;
        int srow = (np & 3) * 256 + (np >> 2);
        bias_p[i] = ((dd == 0) ? (bihf[srow] + bhhf[srow]) : (bihb[srow] + bhhb[srow])) * LOG2E;
    }
}

// x (B,L,E) fp32 -> bf16, same layout
__global__ void convert_x(const float* __restrict__ x, unsigned short* __restrict__ xb) {
    int i = blockIdx.x * 256 + threadIdx.x;     // 16384 blocks
    float4 a = reinterpret_cast<const float4*>(x)[i * 2];
    float4 b = reinterpret_cast<const float4*>(x)[i * 2 + 1];
    uint4 p = { pack2(a.x, a.y), pack2(a.z, a.w), pack2(b.x, b.y), pack2(b.z, b.w) };
    reinterpret_cast<uint4*>(xb)[i] = p;
}

// ---------------------------------------------------------------------------
// pre3[d][b][l][n'] (bf16, b-major), n' = col*4+gate, scaled by LOG2E.
// m97-style: 128x128 tile, BK=32, global_load_lds(16B). M-tile = one b, 128 l.
// ---------------------------------------------------------------------------
__global__ __launch_bounds__(256) void pre_gemm(
    const unsigned short* __restrict__ xb,    // (B,L,E) bf16
    const unsigned short* __restrict__ wp,    // (2048,512) bf16 permuted*LOG2E
    const float* __restrict__ bias_p,         // (2048) permuted*LOG2E
    unsigned short* __restrict__ pre3)        // [2][128][512][1024]
{
    __shared__ unsigned short A_lds[128 * 32];   // [row][k], 64B/row (no pad: DMA linear)
    __shared__ unsigned short B_lds[128 * 32];

    int nt = blockIdx.x, mt = blockIdx.y;
    int tid = threadIdx.x;
    int n0 = nt * 128;
    int b  = mt >> 2, l0 = (mt & 3) * 128;
    int w = tid >> 6, lane = tid & 63;
    int q = lane >> 4, ln = lane & 15;
    int wm = (w >> 1) * 64, wn = (w & 1) * 64;

    f32x4 acc[4][4];
    #pragma unroll
    for (int i = 0; i < 4; ++i)
        #pragma unroll
        for (int j = 0; j < 4; ++j) acc[i][j] = (f32x4){0.f, 0.f, 0.f, 0.f};

    int r_ = tid >> 2, kp = (tid & 3) * 8;
    const unsigned short* asrc0 = xb + ((size_t)b * 512 + l0 + r_) * 512 + kp;
    const unsigned short* asrc1 = asrc0 + (size_t)64 * 512;
    const unsigned short* bsrc0 = wp + (size_t)(n0 + r_) * 512 + kp;
    const unsigned short* bsrc1 = bsrc0 + (size_t)64 * 512;
    unsigned short* adst0 = &A_lds[tid * 8];
    unsigned short* adst1 = &A_lds[2048 + tid * 8];
    unsigned short* bdst0 = &B_lds[tid * 8];
    unsigned short* bdst1 = &B_lds[2048 + tid * 8];

    for (int kc = 0; kc < 16; ++kc) {
        int k0 = kc * 32;
        gl_lds16(asrc0 + k0, adst0);
        gl_lds16(asrc1 + k0, adst1);
        gl_lds16(bsrc0 + k0, bdst0);
        gl_lds16(bsrc1 + k0, bdst1);
        __syncthreads();   // drains vmcnt -> LDS filled

        bf16x8 af[4], bfv[4];
        #pragma unroll
        for (int ms = 0; ms < 4; ++ms)
            af[ms] = *reinterpret_cast<const bf16x8*>(&A_lds[(wm + ms * 16 + ln) * 32 + q * 8]);
        #pragma unroll
        for (int ns = 0; ns < 4; ++ns)
            bfv[ns] = *reinterpret_cast<const bf16x8*>(&B_lds[(wn + ns * 16 + ln) * 32 + q * 8]);
        #pragma unroll
        for (int ms = 0; ms < 4; ++ms)
            #pragma unroll
            for (int ns = 0; ns < 4; ++ns)
                acc[ms][ns] = __builtin_amdgcn_mfma_f32_16x16x32_bf16(af[ms], bfv[ns], acc[ms][ns], 0, 0, 0);
        __syncthreads();   // frag reads done before next DMA overwrites
    }

    #pragma unroll
    for (int ns = 0; ns < 4; ++ns) {
        int n = n0 + wn + ns * 16 + ln;
        float bias = bias_p[n];
        int dsel = n >> 10, np = n & 1023;
        #pragma unroll
        for (int ms = 0; ms < 4; ++ms) {
            #pragma unroll
            for (int rg = 0; rg < 4; ++rg) {
                int l = l0 + wm + ms * 16 + q * 4 + rg;
                pre3[(((size_t)dsel * 128 + b) * 512 + l) * 1024 + np] = f2bf(acc[ms][ns][rg] + bias);
            }
        }
    }
}

// ---------------------------------------------------------------------------
// LSTM scan v9: 256 WGs, one (d,b) per WG (v6 parallelism) + tile remap for
// ZERO-SHUFFLE activation + conflict-free h_lds stride.
//   - wave w owns tiles 2w, 2w+1 (cols 32w..32w+31) for every gate, so all 4
//     gates of its columns come from its OWN 16 MFMAs; the valid output row 0
//     sits in lanes 0-15's acc[g][j][0] -> activation on lanes 0-15, 2 cols
//     each, no ds_bpermute at all. Gate-i MFMAs complete ~700 cyc before
//     gate-o -> activation ALU overlaps remaining MFMA issue.
//   - h_lds row stride 260 B (65 dwords == 1 mod 32): A-frag ds_read_b128
//     bank = (ln+8q)%32 -> exact 2-way aliasing (free). Old 272 B stride was
//     8-way (the measured 1.78e7 SQ_LDS_BANK_CONFLICT, ~136 cyc/step).
//   - A-tile rows 1..15 feed garbage into output rows 1..15, which are never
//     read (row r depends only on A row r) -> no zero-maintenance needed.
//   - lgkm-only barrier (hcat stores / pre3 prefetch stay in flight);
//     NO setprio (hurt the lockstep loop in v8, cf. m190).
// ---------------------------------------------------------------------------
__global__ __launch_bounds__(512, 2) void lstm_scan(
    const unsigned short* __restrict__ pre3,  // [2][128][512][1024] bf16 (scaled)
    const unsigned char* __restrict__ whh8,   // [2][1024][256] fp8 e4m3 (scaled)
    unsigned short* __restrict__ hcat)        // [512][128][512] bf16
{
    __shared__ unsigned char h_lds[2][4160];   // row stride 260 B, 16 rows

    int wg = blockIdx.x;           // 256 = 2 dirs x 128 batch
    int d = wg >> 7, b = wg & 127;
    int tid = threadIdx.x, w = tid >> 6, lane = tid & 63;
    int q = lane >> 4, ln = lane & 15;

    const unsigned char* whh_d = whh8 + (size_t)d * (1024 * 256);
    const unsigned short* pre_wg = pre3 + ((size_t)d * 128 + b) * (512 * 1024);

    // B-frags: wave w owns tiles 2w+j (j=0,1); B[n=(2w+j)*16+ln][k=kc*128+q*32+..]
    i32x8 wh[4][2][2];
    #pragma unroll
    for (int g = 0; g < 4; ++g)
        #pragma unroll
        for (int j = 0; j < 2; ++j) {
            int row = g * 256 + (2 * w + j) * 16 + ln;
            #pragma unroll
            for (int kc = 0; kc < 2; ++kc)
                wh[g][j][kc] = *reinterpret_cast<const i32x8*>(
                    whh_d + (size_t)row * 256 + kc * 128 + q * 32);
        }

    for (int i = tid; i < (2 * 4160) / 4; i += 512) ((int*)h_lds)[i] = 0;

    // activation: lanes 0-15 (q==0) own cols c0 = 32w+ln and c1 = c0+16
    bool act = (lane < 16);
    int c0 = 32 * w + ln;
    int c1 = c0 + 16;

    ushort4 p0[2] = {{0,0,0,0},{0,0,0,0}}, p1[2] = {{0,0,0,0},{0,0,0,0}};
    if (act) {
        int la  = (d == 0) ? 0 : (L_ - 1);
        int lb_ = (d == 0) ? 1 : (L_ - 2);
        p0[0] = *reinterpret_cast<const ushort4*>(pre_wg + (size_t)la * 1024 + c0 * 4);
        p0[1] = *reinterpret_cast<const ushort4*>(pre_wg + (size_t)la * 1024 + c1 * 4);
        p1[0] = *reinterpret_cast<const ushort4*>(pre_wg + (size_t)lb_ * 1024 + c0 * 4);
        p1[1] = *reinterpret_cast<const ushort4*>(pre_wg + (size_t)lb_ * 1024 + c1 * 4);
    }
    __syncthreads();

    float cst[2] = {0.f, 0.f};

    for (int t = 0; t < L_; ++t) {
        int p = t & 1;
        int l = (d == 0) ? t : (L_ - 1 - t);

        // prefetch pre[t+2] (stays in flight across the raw barrier)
        ushort4 p2[2] = {{0,0,0,0},{0,0,0,0}};
        if (act) {
            int t2 = (t + 2 < L_) ? (t + 2) : (L_ - 1);
            int l2 = (d == 0) ? t2 : (L_ - 1 - t2);
            p2[0] = *reinterpret_cast<const ushort4*>(pre_wg + (size_t)l2 * 1024 + c0 * 4);
            p2[1] = *reinterpret_cast<const ushort4*>(pre_wg + (size_t)l2 * 1024 + c1 * 4);
        }

        // ---- MFMA: G = h @ W_hh^T (MX fp8, K=256 = 2 chunks of 128) ----
        f32x4 acc[4][2];
        #pragma unroll
        for (int g = 0; g < 4; ++g) {
            acc[g][0] = (f32x4){0.f, 0.f, 0.f, 0.f};
            acc[g][1] = (f32x4){0.f, 0.f, 0.f, 0.f};
        }
        #pragma unroll
        for (int kc = 0; kc < 2; ++kc) {
            const unsigned char* ab = &h_lds[p][ln * 260 + kc * 128 + q * 32];
            uint4 a0 = *reinterpret_cast<const uint4*>(ab);
            uint4 a1 = *reinterpret_cast<const uint4*>(ab + 16);
            i32x8 af = { (int)a0.x, (int)a0.y, (int)a0.z, (int)a0.w,
                         (int)a1.x, (int)a1.y, (int)a1.z, (int)a1.w };
            #pragma unroll
            for (int g = 0; g < 4; ++g)
                #pragma unroll
                for (int j = 0; j < 2; ++j)
                    acc[g][j] = __builtin_amdgcn_mfma_scale_f32_16x16x128_f8f6f4(
                        af, wh[g][j][kc], acc[g][j], 0, 0,
                        0, 0x7f7f7f7f, 0, 0x7f7f7f7f);
        }

        // ---- activation on lanes 0-15: 2 cols each, gates direct from acc ----
        if (act) {
            #pragma unroll
            for (int j = 0; j < 2; ++j) {
                ushort4 P = p0[j];
                float vi = acc[0][j][0] + bf2f(P.x);
                float vf = acc[1][j][0] + bf2f(P.y);
                float vg = acc[2][j][0] + bf2f(P.z);
                float vo = acc[3][j][0] + bf2f(P.w);
                float ei  = ex2(vi);
                float e2g = ex2(vg + vg);
                float itg = (ei * (e2g - 1.f)) * rcp_((1.f + ei) * (1.f + e2g));  // sigm(i)*tanh(g)
                float sf  = rcp_(1.f + ex2(-vf));
                float cn  = fmaf(sf, cst[j], itg);
                cst[j] = cn;
                float tc  = fmaf(-2.f, rcp_(1.f + ex2((2.f * LOG2E) * cn)), 1.f); // tanh(c)
                float so  = rcp_(1.f + ex2(-vo));
                float hn  = so * tc;
                int c = (j == 0) ? c0 : c1;
                int pk = __builtin_amdgcn_cvt_pk_fp8_f32(hn, hn, 0, false);
                h_lds[p ^ 1][c] = (unsigned char)(pk & 0xff);
                hcat[((size_t)l * 128 + b) * 512 + d * 256 + c] = f2bf(hn);
            }
        }
        // raw barrier: only drain LDS (h writes); global store/load stay in
        // flight (compiler inserts counted vmcnt at their uses).
        asm volatile("s_waitcnt lgkmcnt(0)" ::: "memory");
        __builtin_amdgcn_s_barrier();

        p0[0] = p1[0]; p0[1] = p1[1];
        p1[0] = p2[0]; p1[1] = p2[1];
    }
}

// ---------------------------------------------------------------------------
// emit[b][l][k] = hcat[l][b][:] . w_emit[k][:] + b_emit[k]   (fp32 out)
// ---------------------------------------------------------------------------
__global__ __launch_bounds__(256) void emit_gemm(
    const unsigned short* __restrict__ hcat,   // [L*B][512]
    const unsigned short* __restrict__ wemit,  // [64][512]
    const float* __restrict__ bemit,           // [64]
    float* __restrict__ emit)                  // [B][L][64]
{
    int m0 = blockIdx.x * 64;
    int tid = threadIdx.x, w = tid >> 6, lane = tid & 63;
    int quad = lane >> 4, ln = lane & 15;
    int mrow = m0 + w * 16;

    f32x4 acc[4];
    #pragma unroll
    for (int i = 0; i < 4; ++i) acc[i] = (f32x4){0.f, 0.f, 0.f, 0.f};

    const unsigned short* arow = hcat + (size_t)(mrow + ln) * 512;
    #pragma unroll 4
    for (int kc = 0; kc < 16; ++kc) {
        bf16x8 af = *reinterpret_cast<const bf16x8*>(arow + kc * 32 + quad * 8);
        #pragma unroll
        for (int T = 0; T < 4; ++T) {
            bf16x8 bfv = *reinterpret_cast<const bf16x8*>(wemit + (size_t)(T * 16 + ln) * 512 + kc * 32 + quad * 8);
            acc[T] = __builtin_amdgcn_mfma_f32_16x16x32_bf16(af, bfv, acc[T], 0, 0, 0);
        }
    }
    #pragma unroll
    for (int T = 0; T < 4; ++T) {
        int k = T * 16 + ln;
        float bias = bemit[k];
        #pragma unroll
        for (int rg = 0; rg < 4; ++rg) {
            int m = mrow + quad * 4 + rg;
            int ll = m >> 7, bidx = m & 127;
            emit[((size_t)bidx * L_ + ll) * K_ + k] = acc[T][rg] + bias;
        }
    }
}

// ---------------------------------------------------------------------------
// CRF: per batch row (one wave), 511 sequential steps.
// Single-wave WG -> lgkmcnt(0)-only LDS visibility (no barrier, no vmcnt
// drain of the enext prefetch). 4 independent fma accumulators.
// ---------------------------------------------------------------------------
__global__ __launch_bounds__(64) void crf_kernel(
    const float* __restrict__ emit,    // [B][L][64]
    const int* __restrict__ labels,    // [B][L]
    const float* __restrict__ trans,   // [64][64]
    float* __restrict__ out)           // [B]
{
    __shared__ float els[2][64];
    int b = blockIdx.x, lane = threadIdx.x;
    const float* eb = emit + (size_t)b * L_ * K_;
    const int* lb = labels + (size_t)b * L_;

    float gold = 0.f;
    for (int t = lane; t < L_; t += 64) gold += eb[(size_t)t * K_ + lb[t]];
    for (int t = lane; t < L_ - 1; t += 64) gold += trans[lb[t] * K_ + lb[t + 1]];
    #pragma unroll
    for (int off = 32; off; off >>= 1) gold += __shfl_down(gold, off);

    float expT[64];   // column `lane` of exp(T)
    #pragma unroll
    for (int i = 0; i < 64; ++i) expT[i] = __expf(trans[i * K_ + lane]);

    float dstate = eb[lane];
    float enext = eb[K_ + lane];
    for (int t = 1; t < L_; ++t) {
        float ecur = enext;
        if (t + 1 < L_) enext = eb[(size_t)(t + 1) * K_ + lane];
        float M = __builtin_amdgcn_readfirstlane(dstate);   // cheap shared shift
        float e = __expf(dstate - M);
        float* el = els[t & 1];
        el[lane] = e;
        // single wave: LDS write visibility needs only lgkmcnt(0), no barrier,
        // and crucially no vmcnt(0) drain of the enext prefetch.
        asm volatile("s_waitcnt lgkmcnt(0)" ::: "memory");
        float s0 = 0.f, s1 = 0.f, s2 = 0.f, s3 = 0.f;
        #pragma unroll
        for (int i = 0; i < 64; i += 16) {
            float4 a0 = *reinterpret_cast<const float4*>(&el[i]);
            float4 a1 = *reinterpret_cast<const float4*>(&el[i + 4]);
            float4 a2 = *reinterpret_cast<const float4*>(&el[i + 8]);
            float4 a3 = *reinterpret_cast<const float4*>(&el[i + 12]);
            s0 = fmaf(a0.x, expT[i], s0);      s0 = fmaf(a0.y, expT[i + 1], s0);
            s0 = fmaf(a0.z, expT[i + 2], s0);  s0 = fmaf(a0.w, expT[i + 3], s0);
            s1 = fmaf(a1.x, expT[i + 4], s1);  s1 = fmaf(a1.y, expT[i + 5], s1);
            s1 = fmaf(a1.z, expT[i + 6], s1);  s1 = fmaf(a1.w, expT[i + 7], s1);
            s2 = fmaf(a2.x, expT[i + 8], s2);  s2 = fmaf(a2.y, expT[i + 9], s2);
            s2 = fmaf(a2.z, expT[i + 10], s2); s2 = fmaf(a2.w, expT[i + 11], s2);
            s3 = fmaf(a3.x, expT[i + 12], s3); s3 = fmaf(a3.y, expT[i + 13], s3);
            s3 = fmaf(a3.z, expT[i + 14], s3); s3 = fmaf(a3.w, expT[i + 15], s3);
        }
        dstate = M + __logf((s0 + s1) + (s2 + s3)) + ecur;
    }
    float M = __builtin_amdgcn_readfirstlane(dstate);
    float e = __expf(dstate - M);
    float s = e;
    #pragma unroll
    for (int off = 32; off; off >>= 1) s += __shfl_xor(s, off);
    float logZ = M + __logf(s);
    if (lane == 0) out[b] = -(gold - logZ);
}

// ---------------------------------------------------------------------------
// Workspace layout (bytes). Overlays (disjoint lifetimes):
//   xb aliases hcat; emit aliases pre3 head.
// ---------------------------------------------------------------------------
#define OFF_PRE    ((size_t)0)                        // 268435456
#define OFF_EMIT   OFF_PRE                            // 16777216 (alias)
#define OFF_HCAT   ((size_t)268435456)                // 67108864
#define OFF_XB     OFF_HCAT                           // 67108864 (alias)
#define OFF_WHH8   ((size_t)(OFF_HCAT + 67108864))    // 524288
#define OFF_WEMIT  ((size_t)(OFF_WHH8 + 524288))      // 65536
#define OFF_WP     ((size_t)(OFF_WEMIT + 65536))      // 2097152
#define OFF_BIAS   ((size_t)(OFF_WP + 2097152))       // 8192

extern "C" void kernel_launch(void* const* d_in, const int* in_sizes, int n_in,
                              void* d_out, int out_size, void* d_ws, size_t ws_size,
                              hipStream_t stream) {
    const float* x      = (const float*)d_in[0];
    const int*   labels = (const int*)d_in[1];
    const float* wihf   = (const float*)d_in[2];
    const float* whhf   = (const float*)d_in[3];
    const float* bihf   = (const float*)d_in[4];
    const float* bhhf   = (const float*)d_in[5];
    const float* wihb   = (const float*)d_in[6];
    const float* whhb   = (const float*)d_in[7];
    const float* bihb   = (const float*)d_in[8];
    const float* bhhb   = (const float*)d_in[9];
    const float* wemit  = (const float*)d_in[10];
    const float* bemit  = (const float*)d_in[11];
    const float* trans  = (const float*)d_in[12];
    float* out = (float*)d_out;

    char* ws = (char*)d_ws;
    unsigned short* pre3   = (unsigned short*)(ws + OFF_PRE);
    unsigned short* hcat   = (unsigned short*)(ws + OFF_HCAT);
    unsigned short* xb     = (unsigned short*)(ws + OFF_XB);
    float*          emit   = (float*)(ws + OFF_EMIT);
    unsigned char*  whh8   = (unsigned char*)(ws + OFF_WHH8);
    unsigned short* we_bf  = (unsigned short*)(ws + OFF_WEMIT);
    unsigned short* wp     = (unsigned short*)(ws + OFF_WP);
    float*          bias_p = (float*)(ws + OFF_BIAS);

    setup_convert<<<1024, 256, 0, stream>>>(whhf, whhb, wemit, wihf, wihb,
                                            bihf, bhhf, bihb, bhhb,
                                            whh8, we_bf, wp, bias_p);
    convert_x<<<16384, 256, 0, stream>>>(x, xb);
    pre_gemm<<<dim3(16, 512), 256, 0, stream>>>(xb, wp, bias_p, pre3);
    lstm_scan<<<256, 512, 0, stream>>>(pre3, whh8, hcat);
    emit_gemm<<<1024, 256, 0, stream>>>(hcat, we_bf, bemit, emit);
    crf_kernel<<<128, 64, 0, stream>>>(emit, labels, trans, out);
}

// Round 4
// 1106.821 us; speedup vs baseline: 1.3237x; 1.3237x over previous
//
#include <hip/hip_runtime.h>
#include <hip/hip_bf16.h>

#define B_   128
#define L_   512
#define E_   512
#define H_   256
#define K_   64
#define G4H  1024   // 4*H
#define LOG2E 1.4426950408889634f

typedef __bf16 bf16x8 __attribute__((ext_vector_type(8)));
typedef float  f32x4  __attribute__((ext_vector_type(4)));
typedef int    i32x8  __attribute__((ext_vector_type(8)));

__device__ inline unsigned short f2bf(float f) {
    unsigned int x = __builtin_bit_cast(unsigned int, f);
    unsigned int r = (x + 0x7fffu + ((x >> 16) & 1u)) >> 16;
    return (unsigned short)r;
}
__device__ inline float bf2f(unsigned short u) {
    unsigned int x = ((unsigned int)u) << 16;
    return __builtin_bit_cast(float, x);
}
__device__ inline unsigned int pack2(float lo, float hi) {
    return (unsigned int)f2bf(lo) | ((unsigned int)f2bf(hi) << 16);
}
__device__ inline float ex2(float x) { return __builtin_amdgcn_exp2f(x); }
__device__ inline float rcp_(float x) { return __builtin_amdgcn_rcpf(x); }

// async global->LDS, 16B per lane; LDS dest must be wave-uniform + lane*16
__device__ inline void gl_lds16(const unsigned short* g, unsigned short* l) {
    __builtin_amdgcn_global_load_lds(
        (const __attribute__((address_space(1))) unsigned int*)g,
        (__attribute__((address_space(3))) unsigned int*)l, 16, 0, 0);
}

// ---------------------------------------------------------------------------
// Setup: whh -> fp8 e4m3 scaled by LOG2E; w_emit -> bf16;
// w_ih -> bf16 * LOG2E with gate-interleaved row perm wp[n'=col*4+gate];
// bias_p = (b_ih + b_hh) * LOG2E, permuted.
// ---------------------------------------------------------------------------
__global__ void setup_convert(const float* __restrict__ whh_f, const float* __restrict__ whh_b,
                              const float* __restrict__ wemit,
                              const float* __restrict__ wihf, const float* __restrict__ wihb,
                              const float* __restrict__ bihf, const float* __restrict__ bhhf,
                              const float* __restrict__ bihb, const float* __restrict__ bhhb,
                              unsigned char* __restrict__ whh8,
                              unsigned short* __restrict__ wemit_bf,
                              unsigned short* __restrict__ wp,
                              float* __restrict__ bias_p) {
    int i = blockIdx.x * 256 + threadIdx.x;       // grid 1024*256 = 262144
    if (i < 262144) {
        int j = 2 * i;
        float v0 = (j < 262144) ? whh_f[j] : whh_b[j - 262144];
        float v1 = (j + 1 < 262144) ? whh_f[j + 1] : whh_b[j + 1 - 262144];
        int pk = __builtin_amdgcn_cvt_pk_fp8_f32(v0 * LOG2E, v1 * LOG2E, 0, false);
        ((unsigned short*)whh8)[i] = (unsigned short)(pk & 0xffff);
    }
    if (i < K_ * 2 * H_) wemit_bf[i] = f2bf(wemit[i]);
    if (i < 131072) {
        int rp = i >> 6;            // permuted row 0..2047
        int k8 = (i & 63) * 8;
        int dd = rp >> 10, np = rp & 1023;
        int srow = (np & 3) * 256 + (np >> 2);
        const float* src = (dd == 0 ? wihf : wihb) + (size_t)srow * 512 + k8;
        float4 a  = *reinterpret_cast<const float4*>(src);
        float4 b2 = *reinterpret_cast<const float4*>(src + 4);
        uint4 pk = { pack2(a.x * LOG2E, a.y * LOG2E), pack2(a.z * LOG2E, a.w * LOG2E),
                     pack2(b2.x * LOG2E, b2.y * LOG2E), pack2(b2.z * LOG2E, b2.w * LOG2E) };
        *reinterpret_cast<uint4*>(wp + (size_t)rp * 512 + k8) = pk;
    }
    if (i < 2048) {
        int dd = i >> 10, np = i & 1023;
        int srow = (np & 3) * 256 + (np >> 2);
        bias_p[i] = ((dd == 0) ? (bihf[srow] + bhhf[srow]) : (bihb[srow] + bhhb[srow])) * LOG2E;
    }
}

// x (B,L,E) fp32 -> bf16, same layout
__global__ void convert_x(const float* __restrict__ x, unsigned short* __restrict__ xb) {
    int i = blockIdx.x * 256 + threadIdx.x;     // 16384 blocks
    float4 a = reinterpret_cast<const float4*>(x)[i * 2];
    float4 b = reinterpret_cast<const float4*>(x)[i * 2 + 1];
    uint4 p = { pack2(a.x, a.y), pack2(a.z, a.w), pack2(b.x, b.y), pack2(b.z, b.w) };
    reinterpret_cast<uint4*>(xb)[i] = p;
}

// ---------------------------------------------------------------------------
// pre3[d][b][l][n'] (bf16, b-major), n' = col*4+gate, scaled by LOG2E.
// m97-style: 128x128 tile, BK=32, global_load_lds(16B). M-tile = one b, 128 l.
// ---------------------------------------------------------------------------
__global__ __launch_bounds__(256) void pre_gemm(
    const unsigned short* __restrict__ xb,    // (B,L,E) bf16
    const unsigned short* __restrict__ wp,    // (2048,512) bf16 permuted*LOG2E
    const float* __restrict__ bias_p,         // (2048) permuted*LOG2E
    unsigned short* __restrict__ pre3)        // [2][128][512][1024]
{
    __shared__ unsigned short A_lds[128 * 32];   // [row][k], 64B/row (no pad: DMA linear)
    __shared__ unsigned short B_lds[128 * 32];

    int nt = blockIdx.x, mt = blockIdx.y;
    int tid = threadIdx.x;
    int n0 = nt * 128;
    int b  = mt >> 2, l0 = (mt & 3) * 128;
    int w = tid >> 6, lane = tid & 63;
    int q = lane >> 4, ln = lane & 15;
    int wm = (w >> 1) * 64, wn = (w & 1) * 64;

    f32x4 acc[4][4];
    #pragma unroll
    for (int i = 0; i < 4; ++i)
        #pragma unroll
        for (int j = 0; j < 4; ++j) acc[i][j] = (f32x4){0.f, 0.f, 0.f, 0.f};

    int r_ = tid >> 2, kp = (tid & 3) * 8;
    const unsigned short* asrc0 = xb + ((size_t)b * 512 + l0 + r_) * 512 + kp;
    const unsigned short* asrc1 = asrc0 + (size_t)64 * 512;
    const unsigned short* bsrc0 = wp + (size_t)(n0 + r_) * 512 + kp;
    const unsigned short* bsrc1 = bsrc0 + (size_t)64 * 512;
    unsigned short* adst0 = &A_lds[tid * 8];
    unsigned short* adst1 = &A_lds[2048 + tid * 8];
    unsigned short* bdst0 = &B_lds[tid * 8];
    unsigned short* bdst1 = &B_lds[2048 + tid * 8];

    for (int kc = 0; kc < 16; ++kc) {
        int k0 = kc * 32;
        gl_lds16(asrc0 + k0, adst0);
        gl_lds16(asrc1 + k0, adst1);
        gl_lds16(bsrc0 + k0, bdst0);
        gl_lds16(bsrc1 + k0, bdst1);
        __syncthreads();   // drains vmcnt -> LDS filled

        bf16x8 af[4], bfv[4];
        #pragma unroll
        for (int ms = 0; ms < 4; ++ms)
            af[ms] = *reinterpret_cast<const bf16x8*>(&A_lds[(wm + ms * 16 + ln) * 32 + q * 8]);
        #pragma unroll
        for (int ns = 0; ns < 4; ++ns)
            bfv[ns] = *reinterpret_cast<const bf16x8*>(&B_lds[(wn + ns * 16 + ln) * 32 + q * 8]);
        #pragma unroll
        for (int ms = 0; ms < 4; ++ms)
            #pragma unroll
            for (int ns = 0; ns < 4; ++ns)
                acc[ms][ns] = __builtin_amdgcn_mfma_f32_16x16x32_bf16(af[ms], bfv[ns], acc[ms][ns], 0, 0, 0);
        __syncthreads();   // frag reads done before next DMA overwrites
    }

    #pragma unroll
    for (int ns = 0; ns < 4; ++ns) {
        int n = n0 + wn + ns * 16 + ln;
        float bias = bias_p[n];
        int dsel = n >> 10, np = n & 1023;
        #pragma unroll
        for (int ms = 0; ms < 4; ++ms) {
            #pragma unroll
            for (int rg = 0; rg < 4; ++rg) {
                int l = l0 + wm + ms * 16 + q * 4 + rg;
                pre3[(((size_t)dsel * 128 + b) * 512 + l) * 1024 + np] = f2bf(acc[ms][ns][rg] + bias);
            }
        }
    }
}

// ---------------------------------------------------------------------------
// LSTM scan v10 = v6 structure (256 WGs, one (d,b) per WG, verified @446us)
// with two surgical changes:
//  (1) BROADCAST A-read: output row r of D depends only on A row r, and only
//      row 0 is consumed (via shfl from q=0 lanes). So ALL lanes read row 0
//      of h from LDS (addr = kc*128+q*32, independent of ln) -> 16-lane
//      broadcast, ZERO bank conflicts (was 8-way, 1.78e7/dispatch), and
//      h_lds shrinks to 2x256B. Rows 1-15 of A/D are garbage and never read.
//  (2) s-major MFMA order: 8 MFMAs (s=0) -> issue lo-shfl -> sched_barrier
//      -> 8 MFMAs (s=1) -> hi-shfl. The lo ds_bpermute latency hides under
//      the s=1 MFMA issue window.
// Everything else (activation, __syncthreads, prefetch) is v6-identical.
// ---------------------------------------------------------------------------
__global__ __launch_bounds__(512, 2) void lstm_scan(
    const unsigned short* __restrict__ pre3,  // [2][128][512][1024] bf16 (scaled)
    const unsigned char* __restrict__ whh8,   // [2][1024][256] fp8 e4m3 (scaled)
    unsigned short* __restrict__ hcat)        // [512][128][512] bf16
{
    __shared__ unsigned char h_lds[2][256];   // fp8 h vector, double-buffered

    int wg = blockIdx.x;           // 256 = 2 dirs x 128 batch
    int d = wg >> 7, b = wg & 127;
    int tid = threadIdx.x, w = tid >> 6, lane = tid & 63;
    int q = lane >> 4, ln = lane & 15;

    const unsigned char* whh_d = whh8 + (size_t)d * (1024 * 256);
    const unsigned short* pre_wg = pre3 + ((size_t)d * 128 + b) * (512 * 1024);

    // W_hh B-frags: tile T = g*16 + (w+8s); B[n=T*16+ln][k=kc*128+q*32+j]
    i32x8 wh[4][2][2];
    #pragma unroll
    for (int g = 0; g < 4; ++g)
        #pragma unroll
        for (int s = 0; s < 2; ++s) {
            int row = g * 256 + (w + 8 * s) * 16 + ln;
            #pragma unroll
            for (int kc = 0; kc < 2; ++kc)
                wh[g][s][kc] = *reinterpret_cast<const i32x8*>(
                    whh_d + (size_t)row * 256 + kc * 128 + q * 32);
        }

    if (tid < 128) ((int*)h_lds)[tid] = 0;   // both buffers zeroed (512 B)

    // activation mapping: lanes 0-31 of each wave own col = (w+8*(lane>>4))*16+ln
    bool act = (lane < 32);
    int s_  = (lane >> 4) & 1;
    int col = (w + 8 * s_) * 16 + ln;

    ushort4 p0 = {0,0,0,0}, p1 = {0,0,0,0};
    if (act) {
        int la  = (d == 0) ? 0 : (L_ - 1);
        int lb_ = (d == 0) ? 1 : (L_ - 2);
        p0 = *reinterpret_cast<const ushort4*>(pre_wg + (size_t)la * 1024 + col * 4);
        p1 = *reinterpret_cast<const ushort4*>(pre_wg + (size_t)lb_ * 1024 + col * 4);
    }
    __syncthreads();

    float cst = 0.f;

    for (int t = 0; t < L_; ++t) {
        int p = t & 1;
        int l = (d == 0) ? t : (L_ - 1 - t);

        // prefetch pre[t+2]
        ushort4 p2 = {0,0,0,0};
        if (act) {
            int t2 = (t + 2 < L_) ? (t + 2) : (L_ - 1);
            int l2 = (d == 0) ? t2 : (L_ - 1 - t2);
            p2 = *reinterpret_cast<const ushort4*>(pre_wg + (size_t)l2 * 1024 + col * 4);
        }

        // ---- broadcast A-frags: every lane reads ROW 0 (the real h) ----
        const unsigned char* hb = h_lds[p];
        uint4 a00 = *reinterpret_cast<const uint4*>(hb + q * 32);
        uint4 a01 = *reinterpret_cast<const uint4*>(hb + q * 32 + 16);
        uint4 a10 = *reinterpret_cast<const uint4*>(hb + 128 + q * 32);
        uint4 a11 = *reinterpret_cast<const uint4*>(hb + 128 + q * 32 + 16);
        i32x8 af0 = { (int)a00.x, (int)a00.y, (int)a00.z, (int)a00.w,
                      (int)a01.x, (int)a01.y, (int)a01.z, (int)a01.w };
        i32x8 af1 = { (int)a10.x, (int)a10.y, (int)a10.z, (int)a10.w,
                      (int)a11.x, (int)a11.y, (int)a11.z, (int)a11.w };

        // ---- MFMA: G = h @ W_hh^T (MX fp8, K=256 = 2 chunks of 128) ----
        f32x4 acc[4][2];
        #pragma unroll
        for (int g = 0; g < 4; ++g) {
            acc[g][0] = (f32x4){0.f, 0.f, 0.f, 0.f};
            acc[g][1] = (f32x4){0.f, 0.f, 0.f, 0.f};
        }
        // s=0 group (8 MFMAs)
        #pragma unroll
        for (int g = 0; g < 4; ++g)
            acc[g][0] = __builtin_amdgcn_mfma_scale_f32_16x16x128_f8f6f4(
                af0, wh[g][0][0], acc[g][0], 0, 0, 0, 0x7f7f7f7f, 0, 0x7f7f7f7f);
        #pragma unroll
        for (int g = 0; g < 4; ++g)
            acc[g][0] = __builtin_amdgcn_mfma_scale_f32_16x16x128_f8f6f4(
                af1, wh[g][0][1], acc[g][0], 0, 0, 0, 0x7f7f7f7f, 0, 0x7f7f7f7f);
        // lo-shfl issues now; its latency hides under the s=1 MFMA cluster
        float lo[4];
        #pragma unroll
        for (int g = 0; g < 4; ++g) lo[g] = __shfl(acc[g][0][0], ln);
        __builtin_amdgcn_sched_barrier(0);
        // s=1 group (8 MFMAs)
        #pragma unroll
        for (int g = 0; g < 4; ++g)
            acc[g][1] = __builtin_amdgcn_mfma_scale_f32_16x16x128_f8f6f4(
                af0, wh[g][1][0], acc[g][1], 0, 0, 0, 0x7f7f7f7f, 0, 0x7f7f7f7f);
        #pragma unroll
        for (int g = 0; g < 4; ++g)
            acc[g][1] = __builtin_amdgcn_mfma_scale_f32_16x16x128_f8f6f4(
                af1, wh[g][1][1], acc[g][1], 0, 0, 0, 0x7f7f7f7f, 0, 0x7f7f7f7f);
        float hi[4];
        #pragma unroll
        for (int g = 0; g < 4; ++g) hi[g] = __shfl(acc[g][1][0], ln);

        // ---- activation on lanes 0-31 (1 unit each) ----
        if (act) {
            float vi = (s_ ? hi[0] : lo[0]) + bf2f(p0.x);
            float vf = (s_ ? hi[1] : lo[1]) + bf2f(p0.y);
            float vg = (s_ ? hi[2] : lo[2]) + bf2f(p0.z);
            float vo = (s_ ? hi[3] : lo[3]) + bf2f(p0.w);
            float ei  = ex2(vi);
            float e2g = ex2(vg + vg);
            float itg = (ei * (e2g - 1.f)) * rcp_((1.f + ei) * (1.f + e2g));  // sigm(i)*tanh(g)
            float sf  = rcp_(1.f + ex2(-vf));
            float cn  = fmaf(sf, cst, itg);
            cst = cn;
            float tc  = fmaf(-2.f, rcp_(1.f + ex2((2.f * LOG2E) * cn)), 1.f); // tanh(c)
            float so  = rcp_(1.f + ex2(-vo));
            float hn  = so * tc;
            int pk = __builtin_amdgcn_cvt_pk_fp8_f32(hn, hn, 0, false);
            h_lds[p ^ 1][col] = (unsigned char)(pk & 0xff);
            hcat[((size_t)l * 128 + b) * 512 + d * 256 + col] = f2bf(hn);
        }
        __syncthreads();   // h_lds[p^1] ready for all waves

        p0 = p1; p1 = p2;
    }
}

// ---------------------------------------------------------------------------
// emit[b][l][k] = hcat[l][b][:] . w_emit[k][:] + b_emit[k]   (fp32 out)
// ---------------------------------------------------------------------------
__global__ __launch_bounds__(256) void emit_gemm(
    const unsigned short* __restrict__ hcat,   // [L*B][512]
    const unsigned short* __restrict__ wemit,  // [64][512]
    const float* __restrict__ bemit,           // [64]
    float* __restrict__ emit)                  // [B][L][64]
{
    int m0 = blockIdx.x * 64;
    int tid = threadIdx.x, w = tid >> 6, lane = tid & 63;
    int quad = lane >> 4, ln = lane & 15;
    int mrow = m0 + w * 16;

    f32x4 acc[4];
    #pragma unroll
    for (int i = 0; i < 4; ++i) acc[i] = (f32x4){0.f, 0.f, 0.f, 0.f};

    const unsigned short* arow = hcat + (size_t)(mrow + ln) * 512;
    #pragma unroll 4
    for (int kc = 0; kc < 16; ++kc) {
        bf16x8 af = *reinterpret_cast<const bf16x8*>(arow + kc * 32 + quad * 8);
        #pragma unroll
        for (int T = 0; T < 4; ++T) {
            bf16x8 bfv = *reinterpret_cast<const bf16x8*>(wemit + (size_t)(T * 16 + ln) * 512 + kc * 32 + quad * 8);
            acc[T] = __builtin_amdgcn_mfma_f32_16x16x32_bf16(af, bfv, acc[T], 0, 0, 0);
        }
    }
    #pragma unroll
    for (int T = 0; T < 4; ++T) {
        int k = T * 16 + ln;
        float bias = bemit[k];
        #pragma unroll
        for (int rg = 0; rg < 4; ++rg) {
            int m = mrow + quad * 4 + rg;
            int ll = m >> 7, bidx = m & 127;
            emit[((size_t)bidx * L_ + ll) * K_ + k] = acc[T][rg] + bias;
        }
    }
}

// ---------------------------------------------------------------------------
// CRF: per batch row (one wave), 511 sequential steps.
// Single-wave WG -> lgkmcnt(0)-only LDS visibility (no barrier, no vmcnt
// drain of the enext prefetch). 4 independent fma accumulators.
// ---------------------------------------------------------------------------
__global__ __launch_bounds__(64) void crf_kernel(
    const float* __restrict__ emit,    // [B][L][64]
    const int* __restrict__ labels,    // [B][L]
    const float* __restrict__ trans,   // [64][64]
    float* __restrict__ out)           // [B]
{
    __shared__ float els[2][64];
    int b = blockIdx.x, lane = threadIdx.x;
    const float* eb = emit + (size_t)b * L_ * K_;
    const int* lb = labels + (size_t)b * L_;

    float gold = 0.f;
    for (int t = lane; t < L_; t += 64) gold += eb[(size_t)t * K_ + lb[t]];
    for (int t = lane; t < L_ - 1; t += 64) gold += trans[lb[t] * K_ + lb[t + 1]];
    #pragma unroll
    for (int off = 32; off; off >>= 1) gold += __shfl_down(gold, off);

    float expT[64];   // column `lane` of exp(T)
    #pragma unroll
    for (int i = 0; i < 64; ++i) expT[i] = __expf(trans[i * K_ + lane]);

    float dstate = eb[lane];
    float enext = eb[K_ + lane];
    for (int t = 1; t < L_; ++t) {
        float ecur = enext;
        if (t + 1 < L_) enext = eb[(size_t)(t + 1) * K_ + lane];
        float M = __builtin_amdgcn_readfirstlane(dstate);   // cheap shared shift
        float e = __expf(dstate - M);
        float* el = els[t & 1];
        el[lane] = e;
        // single wave: LDS write visibility needs only lgkmcnt(0), no barrier,
        // and crucially no vmcnt(0) drain of the enext prefetch.
        asm volatile("s_waitcnt lgkmcnt(0)" ::: "memory");
        float s0 = 0.f, s1 = 0.f, s2 = 0.f, s3 = 0.f;
        #pragma unroll
        for (int i = 0; i < 64; i += 16) {
            float4 a0 = *reinterpret_cast<const float4*>(&el[i]);
            float4 a1 = *reinterpret_cast<const float4*>(&el[i + 4]);
            float4 a2 = *reinterpret_cast<const float4*>(&el[i + 8]);
            float4 a3 = *reinterpret_cast<const float4*>(&el[i + 12]);
            s0 = fmaf(a0.x, expT[i], s0);      s0 = fmaf(a0.y, expT[i + 1], s0);
            s0 = fmaf(a0.z, expT[i + 2], s0);  s0 = fmaf(a0.w, expT[i + 3], s0);
            s1 = fmaf(a1.x, expT[i + 4], s1);  s1 = fmaf(a1.y, expT[i + 5], s1);
            s1 = fmaf(a1.z, expT[i + 6], s1);  s1 = fmaf(a1.w, expT[i + 7], s1);
            s2 = fmaf(a2.x, expT[i + 8], s2);  s2 = fmaf(a2.y, expT[i + 9], s2);
            s2 = fmaf(a2.z, expT[i + 10], s2); s2 = fmaf(a2.w, expT[i + 11], s2);
            s3 = fmaf(a3.x, expT[i + 12], s3); s3 = fmaf(a3.y, expT[i + 13], s3);
            s3 = fmaf(a3.z, expT[i + 14], s3); s3 = fmaf(a3.w, expT[i + 15], s3);
        }
        dstate = M + __logf((s0 + s1) + (s2 + s3)) + ecur;
    }
    float M = __builtin_amdgcn_readfirstlane(dstate);
    float e = __expf(dstate - M);
    float s = e;
    #pragma unroll
    for (int off = 32; off; off >>= 1) s += __shfl_xor(s, off);
    float logZ = M + __logf(s);
    if (lane == 0) out[b] = -(gold - logZ);
}

// ---------------------------------------------------------------------------
// Workspace layout (bytes). Overlays (disjoint lifetimes):
//   xb aliases hcat; emit aliases pre3 head.
// ---------------------------------------------------------------------------
#define OFF_PRE    ((size_t)0)                        // 268435456
#define OFF_EMIT   OFF_PRE                            // 16777216 (alias)
#define OFF_HCAT   ((size_t)268435456)                // 67108864
#define OFF_XB     OFF_HCAT                           // 67108864 (alias)
#define OFF_WHH8   ((size_t)(OFF_HCAT + 67108864))    // 524288
#define OFF_WEMIT  ((size_t)(OFF_WHH8 + 524288))      // 65536
#define OFF_WP     ((size_t)(OFF_WEMIT + 65536))      // 2097152
#define OFF_BIAS   ((size_t)(OFF_WP + 2097152))       // 8192

extern "C" void kernel_launch(void* const* d_in, const int* in_sizes, int n_in,
                              void* d_out, int out_size, void* d_ws, size_t ws_size,
                              hipStream_t stream) {
    const float* x      = (const float*)d_in[0];
    const int*   labels = (const int*)d_in[1];
    const float* wihf   = (const float*)d_in[2];
    const float* whhf   = (const float*)d_in[3];
    const float* bihf   = (const float*)d_in[4];
    const float* bhhf   = (const float*)d_in[5];
    const float* wihb   = (const float*)d_in[6];
    const float* whhb   = (const float*)d_in[7];
    const float* bihb   = (const float*)d_in[8];
    const float* bhhb   = (const float*)d_in[9];
    const float* wemit  = (const float*)d_in[10];
    const float* bemit  = (const float*)d_in[11];
    const float* trans  = (const float*)d_in[12];
    float* out = (float*)d_out;

    char* ws = (char*)d_ws;
    unsigned short* pre3   = (unsigned short*)(ws + OFF_PRE);
    unsigned short* hcat   = (unsigned short*)(ws + OFF_HCAT);
    unsigned short* xb     = (unsigned short*)(ws + OFF_XB);
    float*          emit   = (float*)(ws + OFF_EMIT);
    unsigned char*  whh8   = (unsigned char*)(ws + OFF_WHH8);
    unsigned short* we_bf  = (unsigned short*)(ws + OFF_WEMIT);
    unsigned short* wp     = (unsigned short*)(ws + OFF_WP);
    float*          bias_p = (float*)(ws + OFF_BIAS);

    setup_convert<<<1024, 256, 0, stream>>>(whhf, whhb, wemit, wihf, wihb,
                                            bihf, bhhf, bihb, bhhb,
                                            whh8, we_bf, wp, bias_p);
    convert_x<<<16384, 256, 0, stream>>>(x, xb);
    pre_gemm<<<dim3(16, 512), 256, 0, stream>>>(xb, wp, bias_p, pre3);
    lstm_scan<<<256, 512, 0, stream>>>(pre3, whh8, hcat);
    emit_gemm<<<1024, 256, 0, stream>>>(hcat, we_bf, bemit, emit);
    crf_kernel<<<128, 64, 0, stream>>>(emit, labels, trans, out);
}